// Round 1
// baseline (1634.907 us; speedup 1.0000x reference)
//
#include <hip/hip_runtime.h>
#include <math.h>

#define NN 100000
#define NE 1600000
#define D 64
#define DM 32

// ---- edge scatter: agg[dst] += h[src]; optionally cnt[dst] += 1 ----
// 64 lanes per edge, lane d handles feature d. Coalesced 256B read per edge.
template <int DO_COUNT>
__global__ __launch_bounds__(256) void scatter_kernel(
    const float* __restrict__ h,
    const int* __restrict__ src,
    const int* __restrict__ dst,
    float* __restrict__ agg,
    float* __restrict__ cnt,
    int nEdges)
{
    int e = blockIdx.x * 4 + (threadIdx.x >> 6);
    if (e >= nEdges) return;
    int lane = threadIdx.x & 63;
    int s = src[e];
    int t = dst[e];
    float v = h[(size_t)s * D + lane];
    atomicAdd(&agg[(size_t)t * D + lane], v);
    if (DO_COUNT && lane == 0) atomicAdd(&cnt[t], 1.0f);
}

// ---- node update: hout = relu((agg/max(cnt,1)) @ Wl + bl + hin @ Wr) ----
// One wave per node. Weights staged in LDS. Node vectors broadcast via shfl.
__global__ __launch_bounds__(256) void node_update_kernel(
    const float* __restrict__ hin,
    const float* __restrict__ agg,
    const float* __restrict__ cnt,
    const float* __restrict__ Wl,
    const float* __restrict__ bl,
    const float* __restrict__ Wr,
    float* __restrict__ hout,
    int n)
{
    __shared__ float sWl[D * D];
    __shared__ float sWr[D * D];
    for (int i = threadIdx.x; i < D * D; i += 256) {
        sWl[i] = Wl[i];
        sWr[i] = Wr[i];
    }
    __syncthreads();

    int node = blockIdx.x * 4 + (threadIdx.x >> 6);
    if (node >= n) return;
    int lane = threadIdx.x & 63;

    float inv = 1.0f / fmaxf(cnt[node], 1.0f);
    float m  = agg[(size_t)node * D + lane] * inv;
    float xr = hin[(size_t)node * D + lane];

    float acc = bl[lane];
#pragma unroll
    for (int k = 0; k < D; ++k) {
        float a = __shfl(m, k);
        float b = __shfl(xr, k);
        acc += a * sWl[k * D + lane] + b * sWr[k * D + lane];
    }
    hout[(size_t)node * D + lane] = fmaxf(acc, 0.0f);
}

// ---- layer-2 node update fused with MLP head ----
__global__ __launch_bounds__(256) void node_update2_mlp_kernel(
    const float* __restrict__ hin,
    const float* __restrict__ agg,
    const float* __restrict__ cnt,
    const float* __restrict__ W2l,
    const float* __restrict__ b2l,
    const float* __restrict__ W2r,
    const float* __restrict__ Wf1,
    const float* __restrict__ bf1,
    const float* __restrict__ Wf2,
    const float* __restrict__ bf2,
    float* __restrict__ out,
    int n)
{
    __shared__ float sWl[D * D];
    __shared__ float sWr[D * D];
    __shared__ float sF1[D * DM];
    __shared__ float sF2[DM];
    for (int i = threadIdx.x; i < D * D; i += 256) {
        sWl[i] = W2l[i];
        sWr[i] = W2r[i];
    }
    for (int i = threadIdx.x; i < D * DM; i += 256) sF1[i] = Wf1[i];
    if (threadIdx.x < DM) sF2[threadIdx.x] = Wf2[threadIdx.x];
    __syncthreads();

    int node = blockIdx.x * 4 + (threadIdx.x >> 6);
    if (node >= n) return;
    int lane = threadIdx.x & 63;

    float inv = 1.0f / fmaxf(cnt[node], 1.0f);
    float m  = agg[(size_t)node * D + lane] * inv;
    float xr = hin[(size_t)node * D + lane];

    float acc = b2l[lane];
#pragma unroll
    for (int k = 0; k < D; ++k) {
        float a = __shfl(m, k);
        float b = __shfl(xr, k);
        acc += a * sWl[k * D + lane] + b * sWr[k * D + lane];
    }
    float h2 = fmaxf(acc, 0.0f);

    // h3[j] = relu(sum_k h2[k] * Wf1[k*32+j] + bf1[j]) for j in [0,32)
    float acc2 = (lane < DM) ? bf1[lane] : 0.0f;
#pragma unroll
    for (int k = 0; k < D; ++k) {
        float hv = __shfl(h2, k);  // all lanes participate
        if (lane < DM) acc2 += hv * sF1[k * DM + lane];
    }
    float p = (lane < DM) ? fmaxf(acc2, 0.0f) * sF2[lane] : 0.0f;

    // sum across all 64 lanes (upper half contributes zero)
#pragma unroll
    for (int off = 32; off >= 1; off >>= 1) p += __shfl_xor(p, off);

    if (lane == 0) {
        float z = p + bf2[0];
        out[node] = 1.0f / (1.0f + expf(-z));
    }
}

extern "C" void kernel_launch(void* const* d_in, const int* in_sizes, int n_in,
                              void* d_out, int out_size, void* d_ws, size_t ws_size,
                              hipStream_t stream)
{
    const float* x   = (const float*)d_in[0];
    const int*   ei  = (const int*)d_in[1];
    const float* W1l = (const float*)d_in[2];
    const float* b1l = (const float*)d_in[3];
    const float* W1r = (const float*)d_in[4];
    const float* W2l = (const float*)d_in[5];
    const float* b2l = (const float*)d_in[6];
    const float* W2r = (const float*)d_in[7];
    const float* Wf1 = (const float*)d_in[8];
    const float* bf1 = (const float*)d_in[9];
    const float* Wf2 = (const float*)d_in[10];
    const float* bf2 = (const float*)d_in[11];
    float* out = (float*)d_out;

    const int* src = ei;            // edge_index[0]
    const int* dst = ei + NE;       // edge_index[1]

    // workspace layout
    size_t aggBytes = (size_t)NN * D * sizeof(float);   // 25.6 MB
    size_t cntBytes = (size_t)NN * sizeof(float);       // 0.4 MB
    char* ws = (char*)d_ws;
    float* agg = (float*)ws;
    float* cnt = (float*)(ws + aggBytes);
    size_t h1Off = (aggBytes + cntBytes + 255) & ~(size_t)255;
    float* h1 = (float*)(ws + h1Off);

    dim3 blk(256);
    int scatterGrid = (NE + 3) / 4;
    int nodeGrid = (NN + 3) / 4;

    // ---- layer 1 ----
    hipMemsetAsync(agg, 0, aggBytes, stream);
    hipMemsetAsync(cnt, 0, cntBytes, stream);
    scatter_kernel<1><<<scatterGrid, blk, 0, stream>>>(x, src, dst, agg, cnt, NE);
    node_update_kernel<<<nodeGrid, blk, 0, stream>>>(x, agg, cnt, W1l, b1l, W1r, h1, NN);

    // ---- layer 2 ----
    hipMemsetAsync(agg, 0, aggBytes, stream);
    scatter_kernel<0><<<scatterGrid, blk, 0, stream>>>(h1, src, dst, agg, cnt, NE);
    node_update2_mlp_kernel<<<nodeGrid, blk, 0, stream>>>(h1, agg, cnt, W2l, b2l, W2r,
                                                          Wf1, bf1, Wf2, bf2, out, NN);
}

// Round 2
// 976.763 us; speedup vs baseline: 1.6738x; 1.6738x over previous
//
#include <hip/hip_runtime.h>
#include <math.h>

#define NN 100000
#define NE 1600000
#define D 64
#define DM 32
#define PAD 68   // padded row stride (floats) for transposed weights in LDS

__device__ __forceinline__ float bcast(float v, int k) {
    return __uint_as_float(__builtin_amdgcn_readlane(__float_as_uint(v), k));
}

// ---- edge scatter: agg[dst] += h[src]; optionally cnt[dst] += 1 ----
template <int DO_COUNT>
__global__ __launch_bounds__(256) void scatter_kernel(
    const float* __restrict__ h,
    const int* __restrict__ src,
    const int* __restrict__ dst,
    float* __restrict__ agg,
    float* __restrict__ cnt,
    int nEdges)
{
    int e = blockIdx.x * 4 + (threadIdx.x >> 6);
    if (e >= nEdges) return;
    int lane = threadIdx.x & 63;
    int s = src[e];
    int t = dst[e];
    float v = h[(size_t)s * D + lane];
    atomicAdd(&agg[(size_t)t * D + lane], v);
    if (DO_COUNT && lane == 0) atomicAdd(&cnt[t], 1.0f);
}

// ---- node update: hout = relu((agg/max(cnt,1)) @ Wl + bl + hin @ Wr) ----
// Grid-stride over nodes; one wave per node. Weights transposed in LDS
// (row j holds column j of W, contiguous in k, padded stride) -> ds_read_b128.
// Node-vector broadcast via v_readlane (SGPR operand in FMA).
__global__ __launch_bounds__(256) void node_update_kernel(
    const float* __restrict__ hin,
    const float* __restrict__ agg,
    const float* __restrict__ cnt,
    const float* __restrict__ Wl,
    const float* __restrict__ bl,
    const float* __restrict__ Wr,
    float* __restrict__ hout,
    int n)
{
    __shared__ float sWlT[D * PAD];
    __shared__ float sWrT[D * PAD];
    __shared__ float sBl[D];
    for (int i = threadIdx.x; i < D * D; i += 256) {
        int k = i >> 6, j = i & 63;          // global layout W[k][j]
        sWlT[j * PAD + k] = Wl[i];
        sWrT[j * PAD + k] = Wr[i];
    }
    if (threadIdx.x < D) sBl[threadIdx.x] = bl[threadIdx.x];
    __syncthreads();

    int lane = threadIdx.x & 63;
    int wid = threadIdx.x >> 6;
    const float* rowWl = &sWlT[lane * PAD];
    const float* rowWr = &sWrT[lane * PAD];

    for (int node = blockIdx.x * 4 + wid; node < n; node += gridDim.x * 4) {
        float inv = 1.0f / fmaxf(cnt[node], 1.0f);
        float m  = agg[(size_t)node * D + lane] * inv;
        float xr = hin[(size_t)node * D + lane];

        float acc = sBl[lane];
#pragma unroll
        for (int k0 = 0; k0 < D; k0 += 4) {
            float4 wl = *(const float4*)&rowWl[k0];
            float4 wr = *(const float4*)&rowWr[k0];
            acc += bcast(m, k0 + 0) * wl.x + bcast(xr, k0 + 0) * wr.x;
            acc += bcast(m, k0 + 1) * wl.y + bcast(xr, k0 + 1) * wr.y;
            acc += bcast(m, k0 + 2) * wl.z + bcast(xr, k0 + 2) * wr.z;
            acc += bcast(m, k0 + 3) * wl.w + bcast(xr, k0 + 3) * wr.w;
        }
        hout[(size_t)node * D + lane] = fmaxf(acc, 0.0f);
    }
}

// ---- layer-2 node update fused with MLP head ----
__global__ __launch_bounds__(256) void node_update2_mlp_kernel(
    const float* __restrict__ hin,
    const float* __restrict__ agg,
    const float* __restrict__ cnt,
    const float* __restrict__ W2l,
    const float* __restrict__ b2l,
    const float* __restrict__ W2r,
    const float* __restrict__ Wf1,
    const float* __restrict__ bf1,
    const float* __restrict__ Wf2,
    const float* __restrict__ bf2,
    float* __restrict__ out,
    int n)
{
    __shared__ float sWlT[D * PAD];
    __shared__ float sWrT[D * PAD];
    __shared__ float sF1T[DM * PAD];
    __shared__ float sBl[D];
    __shared__ float sBf1[DM];
    __shared__ float sF2[DM];
    __shared__ float sBf2;
    for (int i = threadIdx.x; i < D * D; i += 256) {
        int k = i >> 6, j = i & 63;
        sWlT[j * PAD + k] = W2l[i];
        sWrT[j * PAD + k] = W2r[i];
    }
    for (int i = threadIdx.x; i < D * DM; i += 256) {
        int k = i >> 5, j = i & 31;          // Wf1[k][j]
        sF1T[j * PAD + k] = Wf1[i];
    }
    if (threadIdx.x < D) sBl[threadIdx.x] = b2l[threadIdx.x];
    if (threadIdx.x < DM) {
        sBf1[threadIdx.x] = bf1[threadIdx.x];
        sF2[threadIdx.x] = Wf2[threadIdx.x];
    }
    if (threadIdx.x == 0) sBf2 = bf2[0];
    __syncthreads();

    int lane = threadIdx.x & 63;
    int wid = threadIdx.x >> 6;
    const float* rowWl = &sWlT[lane * PAD];
    const float* rowWr = &sWrT[lane * PAD];
    const float* rowF1 = &sF1T[(lane & 31) * PAD];

    for (int node = blockIdx.x * 4 + wid; node < n; node += gridDim.x * 4) {
        float inv = 1.0f / fmaxf(cnt[node], 1.0f);
        float m  = agg[(size_t)node * D + lane] * inv;
        float xr = hin[(size_t)node * D + lane];

        float acc = sBl[lane];
#pragma unroll
        for (int k0 = 0; k0 < D; k0 += 4) {
            float4 wl = *(const float4*)&rowWl[k0];
            float4 wr = *(const float4*)&rowWr[k0];
            acc += bcast(m, k0 + 0) * wl.x + bcast(xr, k0 + 0) * wr.x;
            acc += bcast(m, k0 + 1) * wl.y + bcast(xr, k0 + 1) * wr.y;
            acc += bcast(m, k0 + 2) * wl.z + bcast(xr, k0 + 2) * wr.z;
            acc += bcast(m, k0 + 3) * wl.w + bcast(xr, k0 + 3) * wr.w;
        }
        float h2 = fmaxf(acc, 0.0f);

        // h3[j] = relu(sum_k h2[k]*Wf1[k][j] + bf1[j]); j = lane (lanes >= 32 idle)
        float acc2 = (lane < DM) ? sBf1[lane] : 0.0f;
#pragma unroll
        for (int k0 = 0; k0 < D; k0 += 4) {
            float4 f1 = *(const float4*)&rowF1[k0];
            float a0 = bcast(h2, k0 + 0);
            float a1 = bcast(h2, k0 + 1);
            float a2 = bcast(h2, k0 + 2);
            float a3 = bcast(h2, k0 + 3);
            if (lane < DM)
                acc2 += a0 * f1.x + a1 * f1.y + a2 * f1.z + a3 * f1.w;
        }
        float p = (lane < DM) ? fmaxf(acc2, 0.0f) * sF2[lane & 31] : 0.0f;
#pragma unroll
        for (int off = 32; off >= 1; off >>= 1) p += __shfl_xor(p, off);

        if (lane == 0) {
            float z = p + sBf2;
            out[node] = 1.0f / (1.0f + expf(-z));
        }
    }
}

extern "C" void kernel_launch(void* const* d_in, const int* in_sizes, int n_in,
                              void* d_out, int out_size, void* d_ws, size_t ws_size,
                              hipStream_t stream)
{
    const float* x   = (const float*)d_in[0];
    const int*   ei  = (const int*)d_in[1];
    const float* W1l = (const float*)d_in[2];
    const float* b1l = (const float*)d_in[3];
    const float* W1r = (const float*)d_in[4];
    const float* W2l = (const float*)d_in[5];
    const float* b2l = (const float*)d_in[6];
    const float* W2r = (const float*)d_in[7];
    const float* Wf1 = (const float*)d_in[8];
    const float* bf1 = (const float*)d_in[9];
    const float* Wf2 = (const float*)d_in[10];
    const float* bf2 = (const float*)d_in[11];
    float* out = (float*)d_out;

    const int* src = ei;            // edge_index[0]
    const int* dst = ei + NE;       // edge_index[1]

    size_t aggBytes = (size_t)NN * D * sizeof(float);
    size_t cntBytes = (size_t)NN * sizeof(float);
    char* ws = (char*)d_ws;
    float* agg = (float*)ws;
    float* cnt = (float*)(ws + aggBytes);
    size_t h1Off = (aggBytes + cntBytes + 255) & ~(size_t)255;
    float* h1 = (float*)(ws + h1Off);

    dim3 blk(256);
    int scatterGrid = (NE + 3) / 4;
    int nodeGrid = 1024;   // grid-stride; ~4 blocks/CU resident

    // ---- layer 1 ----
    hipMemsetAsync(agg, 0, aggBytes, stream);
    hipMemsetAsync(cnt, 0, cntBytes, stream);
    scatter_kernel<1><<<scatterGrid, blk, 0, stream>>>(x, src, dst, agg, cnt, NE);
    node_update_kernel<<<nodeGrid, blk, 0, stream>>>(x, agg, cnt, W1l, b1l, W1r, h1, NN);

    // ---- layer 2 ----
    hipMemsetAsync(agg, 0, aggBytes, stream);
    scatter_kernel<0><<<scatterGrid, blk, 0, stream>>>(h1, src, dst, agg, cnt, NE);
    node_update2_mlp_kernel<<<nodeGrid, blk, 0, stream>>>(h1, agg, cnt, W2l, b2l, W2r,
                                                          Wf1, bf1, Wf2, bf2, out, NN);
}

// Round 3
// 636.744 us; speedup vs baseline: 2.5676x; 1.5340x over previous
//
#include <hip/hip_runtime.h>
#include <math.h>

#define NN 100000
#define NE 1600000
#define D 64
#define DM 32
#define PAD 68            // padded row stride (floats) for transposed weights in LDS
#define SCAN_CHUNK 1024   // elements per scan block
#define NBLK_SCAN ((NN + SCAN_CHUNK - 1) / SCAN_CHUNK)   // 98

__device__ __forceinline__ float bcastf(float v, int k) {
    return __uint_as_float(__builtin_amdgcn_readlane(__float_as_uint(v), k));
}
__device__ __forceinline__ int bcasti(int v, int k) {
    return (int)__builtin_amdgcn_readlane((unsigned)v, k);
}

// ---------- CSR build ----------
__global__ __launch_bounds__(256) void hist_kernel(
    const int* __restrict__ dst, int* __restrict__ hist, int nEdges)
{
    for (int e = blockIdx.x * 256 + threadIdx.x; e < nEdges; e += gridDim.x * 256)
        atomicAdd(&hist[dst[e]], 1);
}

__global__ __launch_bounds__(256) void block_sum_kernel(
    const int* __restrict__ hist, int* __restrict__ partials, int n)
{
    __shared__ int red[256];
    int t = threadIdx.x;
    int base = blockIdx.x * SCAN_CHUNK + t * 4;
    int tot = 0;
#pragma unroll
    for (int k = 0; k < 4; ++k)
        if (base + k < n) tot += hist[base + k];
    red[t] = tot;
    __syncthreads();
    for (int off = 128; off >= 1; off >>= 1) {
        if (t < off) red[t] += red[t + off];
        __syncthreads();
    }
    if (t == 0) partials[blockIdx.x] = red[0];
}

__global__ __launch_bounds__(128) void scan_partials_kernel(
    const int* __restrict__ partials, int* __restrict__ pscan, int nb)
{
    __shared__ int l[128];
    int t = threadIdx.x;
    if (t < nb) l[t] = partials[t];
    __syncthreads();
    if (t == 0) {
        int run = 0;
        for (int i = 0; i < nb; ++i) { int tmp = l[i]; l[i] = run; run += tmp; }
    }
    __syncthreads();
    if (t < nb) pscan[t] = l[t];
}

__global__ __launch_bounds__(256) void scan_chunk_kernel(
    const int* __restrict__ hist, const int* __restrict__ pscan,
    int* __restrict__ rowBeg, int* __restrict__ cursor, int n)
{
    __shared__ int lsum[256];
    int t = threadIdx.x;
    int base = blockIdx.x * SCAN_CHUNK + t * 4;
    int v[4];
    int tot = 0;
#pragma unroll
    for (int k = 0; k < 4; ++k) {
        v[k] = (base + k < n) ? hist[base + k] : 0;
        tot += v[k];
    }
    lsum[t] = tot;
    __syncthreads();
    // Hillis-Steele inclusive scan over 256 thread totals
    for (int off = 1; off < 256; off <<= 1) {
        int x = (t >= off) ? lsum[t - off] : 0;
        __syncthreads();
        lsum[t] += x;
        __syncthreads();
    }
    int run = pscan[blockIdx.x] + lsum[t] - tot;
#pragma unroll
    for (int k = 0; k < 4; ++k) {
        if (base + k < n) {
            rowBeg[base + k] = run;
            cursor[base + k] = run;
            run += v[k];
        }
    }
}

__global__ __launch_bounds__(256) void fill_kernel(
    const int* __restrict__ src, const int* __restrict__ dst,
    int* __restrict__ cursor, int* __restrict__ sortedSrc, int nEdges)
{
    for (int e = blockIdx.x * 256 + threadIdx.x; e < nEdges; e += gridDim.x * 256) {
        int pos = atomicAdd(&cursor[dst[e]], 1);
        sortedSrc[pos] = src[e];
    }
}

// ---------- gather helper: sum h[src] rows for one node's segment ----------
__device__ __forceinline__ float gather_sum(
    const float* __restrict__ h, const int* __restrict__ sortedSrc,
    int beg, int deg, int lane)
{
    float acc = 0.0f;
    for (int c = 0; c < deg; c += 64) {
        int cl = min(64, deg - c);
        int idx = (lane < cl) ? sortedSrc[beg + c + lane] : 0;
        int j = 0;
        for (; j + 4 <= cl; j += 4) {
            int s0 = bcasti(idx, j + 0);
            int s1 = bcasti(idx, j + 1);
            int s2 = bcasti(idx, j + 2);
            int s3 = bcasti(idx, j + 3);
            float v0 = h[(size_t)s0 * D + lane];
            float v1 = h[(size_t)s1 * D + lane];
            float v2 = h[(size_t)s2 * D + lane];
            float v3 = h[(size_t)s3 * D + lane];
            acc += v0; acc += v1; acc += v2; acc += v3;
        }
        for (; j < cl; ++j) {
            int s = bcasti(idx, j);
            acc += h[(size_t)s * D + lane];
        }
    }
    return acc;
}

// ---------- fused layer 1: gather-mean + GEMV + relu ----------
__global__ __launch_bounds__(256) void sage_layer1_kernel(
    const float* __restrict__ hin,
    const int* __restrict__ rowBeg, const int* __restrict__ deg,
    const int* __restrict__ sortedSrc,
    const float* __restrict__ Wl, const float* __restrict__ bl,
    const float* __restrict__ Wr,
    float* __restrict__ hout, int n)
{
    __shared__ float sWlT[D * PAD];
    __shared__ float sWrT[D * PAD];
    __shared__ float sBl[D];
    for (int i = threadIdx.x; i < D * D; i += 256) {
        int k = i >> 6, j = i & 63;
        sWlT[j * PAD + k] = Wl[i];
        sWrT[j * PAD + k] = Wr[i];
    }
    if (threadIdx.x < D) sBl[threadIdx.x] = bl[threadIdx.x];
    __syncthreads();

    int lane = threadIdx.x & 63;
    int wid = threadIdx.x >> 6;
    const float* rowWl = &sWlT[lane * PAD];
    const float* rowWr = &sWrT[lane * PAD];

    for (int node = blockIdx.x * 4 + wid; node < n; node += gridDim.x * 4) {
        int dg = deg[node];
        float sum = gather_sum(hin, sortedSrc, rowBeg[node], dg, lane);
        float inv = (dg > 0) ? (1.0f / (float)dg) : 0.0f;
        float m = sum * inv;
        float xr = hin[(size_t)node * D + lane];

        float acc = sBl[lane];
#pragma unroll
        for (int k0 = 0; k0 < D; k0 += 4) {
            float4 wl = *(const float4*)&rowWl[k0];
            float4 wr = *(const float4*)&rowWr[k0];
            acc += bcastf(m, k0 + 0) * wl.x + bcastf(xr, k0 + 0) * wr.x;
            acc += bcastf(m, k0 + 1) * wl.y + bcastf(xr, k0 + 1) * wr.y;
            acc += bcastf(m, k0 + 2) * wl.z + bcastf(xr, k0 + 2) * wr.z;
            acc += bcastf(m, k0 + 3) * wl.w + bcastf(xr, k0 + 3) * wr.w;
        }
        hout[(size_t)node * D + lane] = fmaxf(acc, 0.0f);
    }
}

// ---------- fused layer 2 + MLP head ----------
__global__ __launch_bounds__(256) void sage_layer2_mlp_kernel(
    const float* __restrict__ hin,
    const int* __restrict__ rowBeg, const int* __restrict__ deg,
    const int* __restrict__ sortedSrc,
    const float* __restrict__ W2l, const float* __restrict__ b2l,
    const float* __restrict__ W2r,
    const float* __restrict__ Wf1, const float* __restrict__ bf1,
    const float* __restrict__ Wf2, const float* __restrict__ bf2,
    float* __restrict__ out, int n)
{
    __shared__ float sWlT[D * PAD];
    __shared__ float sWrT[D * PAD];
    __shared__ float sF1T[DM * PAD];
    __shared__ float sBl[D];
    __shared__ float sBf1[DM];
    __shared__ float sF2[DM];
    __shared__ float sBf2;
    for (int i = threadIdx.x; i < D * D; i += 256) {
        int k = i >> 6, j = i & 63;
        sWlT[j * PAD + k] = W2l[i];
        sWrT[j * PAD + k] = W2r[i];
    }
    for (int i = threadIdx.x; i < D * DM; i += 256) {
        int k = i >> 5, j = i & 31;
        sF1T[j * PAD + k] = Wf1[i];
    }
    if (threadIdx.x < D) sBl[threadIdx.x] = b2l[threadIdx.x];
    if (threadIdx.x < DM) {
        sBf1[threadIdx.x] = bf1[threadIdx.x];
        sF2[threadIdx.x] = Wf2[threadIdx.x];
    }
    if (threadIdx.x == 0) sBf2 = bf2[0];
    __syncthreads();

    int lane = threadIdx.x & 63;
    int wid = threadIdx.x >> 6;
    const float* rowWl = &sWlT[lane * PAD];
    const float* rowWr = &sWrT[lane * PAD];
    const float* rowF1 = &sF1T[(lane & 31) * PAD];

    for (int node = blockIdx.x * 4 + wid; node < n; node += gridDim.x * 4) {
        int dg = deg[node];
        float sum = gather_sum(hin, sortedSrc, rowBeg[node], dg, lane);
        float inv = (dg > 0) ? (1.0f / (float)dg) : 0.0f;
        float m = sum * inv;
        float xr = hin[(size_t)node * D + lane];

        float acc = sBl[lane];
#pragma unroll
        for (int k0 = 0; k0 < D; k0 += 4) {
            float4 wl = *(const float4*)&rowWl[k0];
            float4 wr = *(const float4*)&rowWr[k0];
            acc += bcastf(m, k0 + 0) * wl.x + bcastf(xr, k0 + 0) * wr.x;
            acc += bcastf(m, k0 + 1) * wl.y + bcastf(xr, k0 + 1) * wr.y;
            acc += bcastf(m, k0 + 2) * wl.z + bcastf(xr, k0 + 2) * wr.z;
            acc += bcastf(m, k0 + 3) * wl.w + bcastf(xr, k0 + 3) * wr.w;
        }
        float h2 = fmaxf(acc, 0.0f);

        float acc2 = (lane < DM) ? sBf1[lane] : 0.0f;
#pragma unroll
        for (int k0 = 0; k0 < D; k0 += 4) {
            float4 f1 = *(const float4*)&rowF1[k0];
            float a0 = bcastf(h2, k0 + 0);
            float a1 = bcastf(h2, k0 + 1);
            float a2 = bcastf(h2, k0 + 2);
            float a3 = bcastf(h2, k0 + 3);
            if (lane < DM)
                acc2 += a0 * f1.x + a1 * f1.y + a2 * f1.z + a3 * f1.w;
        }
        float p = (lane < DM) ? fmaxf(acc2, 0.0f) * sF2[lane & 31] : 0.0f;
#pragma unroll
        for (int off = 32; off >= 1; off >>= 1) p += __shfl_xor(p, off);

        if (lane == 0) {
            float z = p + sBf2;
            out[node] = 1.0f / (1.0f + expf(-z));
        }
    }
}

extern "C" void kernel_launch(void* const* d_in, const int* in_sizes, int n_in,
                              void* d_out, int out_size, void* d_ws, size_t ws_size,
                              hipStream_t stream)
{
    const float* x   = (const float*)d_in[0];
    const int*   ei  = (const int*)d_in[1];
    const float* W1l = (const float*)d_in[2];
    const float* b1l = (const float*)d_in[3];
    const float* W1r = (const float*)d_in[4];
    const float* W2l = (const float*)d_in[5];
    const float* b2l = (const float*)d_in[6];
    const float* W2r = (const float*)d_in[7];
    const float* Wf1 = (const float*)d_in[8];
    const float* bf1 = (const float*)d_in[9];
    const float* Wf2 = (const float*)d_in[10];
    const float* bf2 = (const float*)d_in[11];
    float* out = (float*)d_out;

    const int* src = ei;            // edge_index[0]
    const int* dst = ei + NE;       // edge_index[1]

    // ---- workspace layout (all 256B aligned) ----
    char* ws = (char*)d_ws;
    size_t off = 0;
    auto alloc = [&](size_t bytes) {
        char* p = ws + off;
        off = (off + bytes + 255) & ~(size_t)255;
        return p;
    };
    int* hist      = (int*)alloc((size_t)NN * sizeof(int));
    int* rowBeg    = (int*)alloc((size_t)NN * sizeof(int));
    int* cursor    = (int*)alloc((size_t)NN * sizeof(int));
    int* partials  = (int*)alloc(128 * sizeof(int));
    int* pscan     = (int*)alloc(128 * sizeof(int));
    int* sortedSrc = (int*)alloc((size_t)NE * sizeof(int));
    float* h1      = (float*)alloc((size_t)NN * D * sizeof(float));

    dim3 blk(256);

    // ---- CSR build (shared by both layers) ----
    hipMemsetAsync(hist, 0, (size_t)NN * sizeof(int), stream);
    hist_kernel<<<2048, blk, 0, stream>>>(dst, hist, NE);
    block_sum_kernel<<<NBLK_SCAN, blk, 0, stream>>>(hist, partials, NN);
    scan_partials_kernel<<<1, 128, 0, stream>>>(partials, pscan, NBLK_SCAN);
    scan_chunk_kernel<<<NBLK_SCAN, blk, 0, stream>>>(hist, pscan, rowBeg, cursor, NN);
    fill_kernel<<<2048, blk, 0, stream>>>(src, dst, cursor, sortedSrc, NE);

    // ---- layer 1 ----
    sage_layer1_kernel<<<1024, blk, 0, stream>>>(x, rowBeg, hist, sortedSrc,
                                                 W1l, b1l, W1r, h1, NN);
    // ---- layer 2 + MLP ----
    sage_layer2_mlp_kernel<<<1024, blk, 0, stream>>>(h1, rowBeg, hist, sortedSrc,
                                                     W2l, b2l, W2r,
                                                     Wf1, bf1, Wf2, bf2, out, NN);
}